// Round 13
// baseline (870.554 us; speedup 1.0000x reference)
//
#include <hip/hip_runtime.h>
#include <math.h>

// Problem constants
#define B_      64
#define L_      256
#define V_      30000
#define E_      300
#define H_      200
#define G4_     800     // 4*H
#define ENC_    400
#define NH_     4
#define DH_     100
#define SCALING_ 1000.0f

__device__ __forceinline__ float sigmoidf_(float x) { return 1.0f / (1.0f + expf(-x)); }

// ---------------- block reductions (256 threads = 4 waves) ----------------
__device__ __forceinline__ float blockSum256(float v, float* red) {
    for (int off = 32; off > 0; off >>= 1) v += __shfl_down(v, off);
    __syncthreads();
    if ((threadIdx.x & 63) == 0) red[threadIdx.x >> 6] = v;
    __syncthreads();
    return red[0] + red[1] + red[2] + red[3];
}

// ---------------- fused front kernel ----------------
// Blocks [0,1664):     xproj GEMM tiles — 128x128 tile, 8x8 micro
//                      (4 ds_read_b128 per 64 FMA = 16 FMA/read, was 10.7;
//                      A-panel re-read 13x, was 25x). Last col-block guarded
//                      (cols 1600..1663 dead). 800%8==0 -> a thread's 8 cols
//                      never straddle the Wi_f/Wi_b seam. K-order unchanged
//                      -> bit-identical results. __launch_bounds__(256,2)
//                      caps VGPR at 256 (acc64+operands ~100, no spill).
// Blocks [1664,1728):  prep (lengths+budget)
// Blocks [1728,1741):  Weff (w2 recomputed cooperatively in LDS)
// Blocks [1741,2991):  Wh gate-interleave pack
#define GTM 128
#define GTN 128
#define GKC 16
#define SA_LD (GTM + 4)
#define SB_LD (GTN + 8)
#define FR_GEMM  1664               // 128 row-blocks x 13 col-blocks
#define FR_PREP  (FR_GEMM + 64)     // 1728
#define FR_WEFF  (FR_PREP + 13)     // 1741
#define FR_PACK  (FR_WEFF + 1250)   // 2991 = grid size
__global__ __launch_bounds__(256, 2) void k_front(const int* __restrict__ x,
        const float* __restrict__ embW,
        const float* __restrict__ Wi_f, const float* __restrict__ b_f,
        const float* __restrict__ Wi_b, const float* __restrict__ b_b,
        float* __restrict__ xproj,
        const void* __restrict__ maskraw, int* __restrict__ lengths,
        float* __restrict__ budget,
        const float* __restrict__ Wk, const float* __restrict__ Wv,
        const float* __restrict__ q, const float* __restrict__ Wo,
        const float* __restrict__ outW, float* __restrict__ Weff,
        const float* __restrict__ Wh_f, const float* __restrict__ Wh_b,
        float* __restrict__ Wp) {
    __shared__ float sA[GKC * SA_LD];
    __shared__ float sB[GKC * SB_LD];
    __shared__ int srow[GTM];
    __shared__ float sOW[ENC_];
    __shared__ float sW2[ENC_];
    __shared__ float red[4];
    int tid = threadIdx.x;
    int blk = blockIdx.x;

    if (blk < FR_GEMM) {
        // ---------------- xproj GEMM tile: 128x128, 8x8 micro --------------
        int rowb = blk & 127, colb = blk >> 7;
        int tm0 = rowb * GTM;
        int tn0 = colb * GTN;
        if (tid < GTM) srow[tid] = x[tm0 + tid];
        __syncthreads();
        int tx = tid & 15, ty = tid >> 4;
        float acc[8][8];
#pragma unroll
        for (int u = 0; u < 8; u++)
#pragma unroll
            for (int v = 0; v < 8; v++) acc[u][v] = 0.0f;

        int mm = tid >> 1, kk8 = (tid & 1) * 8;
        int kkB = tid >> 4, c8 = (tid & 15) * 8;
        int colB = tn0 + c8;
        bool bok = (colB < 2 * G4_);
        const float* bbase = bok ? ((colB < G4_) ? (Wi_f + colB)
                                                 : (Wi_b + (colB - G4_)))
                                 : Wi_f;

        for (int k0 = 0; k0 < E_; k0 += GKC) {
            // A stage: thread's row mm, k-range [k0+kk8, +8), transposed
            const float* arow = embW + (size_t)srow[mm] * E_ + k0 + kk8;
            if (k0 + GKC <= E_) {
                float4 a0 = *(const float4*)(arow);
                float4 a1 = *(const float4*)(arow + 4);
                sA[(kk8 + 0) * SA_LD + mm] = a0.x;
                sA[(kk8 + 1) * SA_LD + mm] = a0.y;
                sA[(kk8 + 2) * SA_LD + mm] = a0.z;
                sA[(kk8 + 3) * SA_LD + mm] = a0.w;
                sA[(kk8 + 4) * SA_LD + mm] = a1.x;
                sA[(kk8 + 5) * SA_LD + mm] = a1.y;
                sA[(kk8 + 6) * SA_LD + mm] = a1.z;
                sA[(kk8 + 7) * SA_LD + mm] = a1.w;
            } else {
#pragma unroll
                for (int i = 0; i < 8; i++) {
                    int k = k0 + kk8 + i;
                    sA[(kk8 + i) * SA_LD + mm] = (k < E_) ? arow[i] : 0.0f;
                }
            }
            // B stage: row kB, thread's 8 cols (guarded)
            {
                int kB = k0 + kkB;
                float4 bv0 = make_float4(0.f, 0.f, 0.f, 0.f);
                float4 bv1 = make_float4(0.f, 0.f, 0.f, 0.f);
                if (bok && kB < E_) {
                    bv0 = *(const float4*)(bbase + (size_t)kB * G4_);
                    bv1 = *(const float4*)(bbase + (size_t)kB * G4_ + 4);
                }
                *(float4*)&sB[kkB * SB_LD + c8] = bv0;
                *(float4*)&sB[kkB * SB_LD + c8 + 4] = bv1;
            }
            __syncthreads();
#pragma unroll
            for (int kk2 = 0; kk2 < GKC; kk2++) {
                float4 a0 = *(const float4*)&sA[kk2 * SA_LD + ty * 8];
                float4 a1 = *(const float4*)&sA[kk2 * SA_LD + ty * 8 + 4];
                float4 b0 = *(const float4*)&sB[kk2 * SB_LD + tx * 8];
                float4 b1 = *(const float4*)&sB[kk2 * SB_LD + tx * 8 + 4];
                float av[8] = {a0.x, a0.y, a0.z, a0.w, a1.x, a1.y, a1.z, a1.w};
                float bv[8] = {b0.x, b0.y, b0.z, b0.w, b1.x, b1.y, b1.z, b1.w};
#pragma unroll
                for (int u = 0; u < 8; u++)
#pragma unroll
                    for (int v = 0; v < 8; v++)
                        acc[u][v] = fmaf(av[u], bv[v], acc[u][v]);
            }
            __syncthreads();
        }
        int col = tn0 + tx * 8;
        if (col < 2 * G4_) {
            float4 bias0, bias1;
            if (col < G4_) {
                bias0 = *(const float4*)(b_f + col);
                bias1 = *(const float4*)(b_f + col + 4);
            } else {
                bias0 = *(const float4*)(b_b + (col - G4_));
                bias1 = *(const float4*)(b_b + (col - G4_) + 4);
            }
#pragma unroll
            for (int u = 0; u < 8; u++) {
                int m = tm0 + ty * 8 + u;
                float4 o0, o1;
                o0.x = acc[u][0] + bias0.x; o0.y = acc[u][1] + bias0.y;
                o0.z = acc[u][2] + bias0.z; o0.w = acc[u][3] + bias0.w;
                o1.x = acc[u][4] + bias1.x; o1.y = acc[u][5] + bias1.y;
                o1.z = acc[u][6] + bias1.z; o1.w = acc[u][7] + bias1.w;
                *(float4*)&xproj[(size_t)m * 1600 + col] = o0;
                *(float4*)&xproj[(size_t)m * 1600 + col + 4] = o1;
            }
        }
    } else if (blk < FR_PREP) {
        // ---------------- prep: lengths + budget ---------------------------
        int b = blk - FR_GEMM;
        const unsigned char* mb = (const unsigned char*)maskraw;
        bool is_byte = (mb[1] != 0);
        const int* mi = (const int*)maskraw;
        int v = is_byte ? (int)mb[b * L_ + tid] : mi[b * L_ + tid];
        float cnt = blockSum256((v != 0) ? 1.0f : 0.0f, red);
        if (tid == 0) {
            int c = (int)(cnt + 0.5f);
            lengths[b] = c;
            budget[b] = rintf(0.2f * (float)c);
        }
    } else if (blk < FR_WEFF) {
        // ---------------- Weff (w2 recomputed cooperatively) ---------------
        for (int i = tid; i < ENC_; i += 256) sOW[i] = outW[i];
        __syncthreads();
        for (int e2 = tid; e2 < ENC_; e2 += 256) {
            float s = 0.0f;
            for (int j2 = 0; j2 < ENC_; j2++)
                s = fmaf(Wo[(size_t)e2 * ENC_ + j2], sOW[j2], s);
            sW2[e2] = s;
        }
        __syncthreads();
        int idx = (blk - FR_PREP) * 256 + tid;
        if (idx < ENC_ * 8) {
            int e = idx >> 3, c = idx & 7;
            int h = c & 3;
            bool isV = (c >= 4);
            const float* M = isV ? Wv : Wk;
            float s = 0.0f;
            for (int d = 0; d < DH_; d++) {
                float wq = isV ? sW2[h * DH_ + d] : q[h * DH_ + d];
                s = fmaf(M[(size_t)e * ENC_ + h * DH_ + d], wq, s);
            }
            Weff[idx] = s;
        }
    } else {
        // ---------------- pack Wh gate-interleaved -------------------------
        int idx = (blk - FR_WEFF) * 256 + tid;   // covers 2*200*200*4 = 320000
        if (idx < 2 * H_ * H_ * 4) {
            int dir = idx / (H_ * H_ * 4);
            int r = idx % (H_ * H_ * 4);
            int k = r / (H_ * 4);
            int r2 = r % (H_ * 4);
            int j = r2 >> 2, g = r2 & 3;
            const float* Wh = dir ? Wh_b : Wh_f;
            Wp[idx] = Wh[(size_t)k * G4_ + g * H_ + j];
        }
    }
}

// ---------------- biLSTM v7: pair-split + exchange hidden under own-half matvec ----
// 256 blocks x 512 threads, cooperative (1 block/CU). 64-bit {tag,h} relaxed
// agent atomics, parity slots. Wave-role split: poll at top of step hidden
// under own-half matvec; monotonic LDS release counter.
// Verified-best k_lstm (499 us). Further attempts all regressed on HW:
// dual-publish L2 fast path (+125), store/load micro-reorder (+22),
// lgkm-only barriers + 4-deep poll (+49), dual-chain-per-pair (+461).
// Single-CU impossible: 640 KB weights > 512 KB/CU register file.
#define KS2 50
__global__ __launch_bounds__(512, 2) void k_lstm(const float* __restrict__ xproj,
        const float4* __restrict__ Wp, const int* __restrict__ lengths,
        float* __restrict__ hf, float* __restrict__ hb,
        unsigned long long* __restrict__ hxS) {
    int pid = blockIdx.x;                 // 0..255
    int chain = pid & 127;
    int half = pid >> 7;
    int partner = pid ^ 128;              // same XCD under %8 round-robin
    int b = chain >> 1, dir = chain & 1;
    int jbase = half * 100;
    const float4* W = Wp + (size_t)dir * H_ * H_;
    float* hout = dir ? hb : hf;
    int len = lengths[b];
    __shared__ float sh[256];             // full h(t), 200 used
    __shared__ float4 sPart[4][128];      // [q][j] partial gate quads
    __shared__ int scnt;                  // monotonic poll-release counter
    int tid = threadIdx.x;
    int q = tid >> 7, j = tid & 127;
    bool act = (j < 100);
    int u = jbase + j;
    bool partnerQ = ((q >> 1) == (half ^ 1));   // this q-slice reads partner half
    int pq0 = (half ^ 1) * 2;                    // first partner-q group

    // preload this thread's weight half-slice into registers (stays resident)
    float4 w[KS2];
    if (act) {
        const float4* wp = W + (size_t)(q * KS2) * H_ + u;
#pragma unroll
        for (int k = 0; k < KS2; k++) w[k] = wp[(size_t)k * H_];
    }
    if (tid < H_) sh[tid] = 0.0f;
    if (tid == 0) scnt = 0;
    float c = 0.0f;
    float hv_prev = 0.0f;
    int t_prev = -1;
    __syncthreads();
    const float* xp = xproj + (size_t)b * L_ * 1600 + dir * G4_;
    const float4* h4 = (const float4*)(sh + q * KS2);
    const float2* h2t = (const float2*)(sh + q * KS2 + 48);

    for (int s = 0; s < len; s++) {
        int t = dir ? (len - 1 - s) : s;
        // previous step's HBM store, drained under this step's matvec
        if (tid < 100 && t_prev >= 0)
            hout[((size_t)b * L_ + t_prev) * H_ + jbase + tid] = hv_prev;
        // pollers: stage partner h(s-1) into sh, then release via LDS counter
        if (s > 0 && q == pq0 && j < 100) {
            size_t idx = ((size_t)(((s - 1) & 1) * 256 + partner)) * 128 + j;
            unsigned long long got;
            do {
                got = __hip_atomic_load(&hxS[idx], __ATOMIC_RELAXED,
                                        __HIP_MEMORY_SCOPE_AGENT);
            } while ((unsigned)(got >> 32) != (unsigned)s);
            sh[(half ^ 1) * 100 + j] = __uint_as_float((unsigned)got);
            __threadfence_block();
            __hip_atomic_fetch_add(&scnt, 1, __ATOMIC_RELAXED,
                                   __HIP_MEMORY_SCOPE_WORKGROUP);
        }
        if (act) {
            if (partnerQ && s > 0) {
                int target = 100 * s;
                while (__hip_atomic_load(&scnt, __ATOMIC_RELAXED,
                                         __HIP_MEMORY_SCOPE_WORKGROUP) < target) {}
            }
            float xv = xp[(size_t)t * 1600 + q * H_ + u];
            float4 acc = make_float4(0.f, 0.f, 0.f, 0.f);
#pragma unroll
            for (int k4 = 0; k4 < 12; k4++) {
                float4 hk = h4[k4];
                const float4 w0 = w[k4 * 4 + 0], w1 = w[k4 * 4 + 1];
                const float4 w2 = w[k4 * 4 + 2], w3 = w[k4 * 4 + 3];
                acc.x = fmaf(hk.x, w0.x, acc.x); acc.y = fmaf(hk.x, w0.y, acc.y);
                acc.z = fmaf(hk.x, w0.z, acc.z); acc.w = fmaf(hk.x, w0.w, acc.w);
                acc.x = fmaf(hk.y, w1.x, acc.x); acc.y = fmaf(hk.y, w1.y, acc.y);
                acc.z = fmaf(hk.y, w1.z, acc.z); acc.w = fmaf(hk.y, w1.w, acc.w);
                acc.x = fmaf(hk.z, w2.x, acc.x); acc.y = fmaf(hk.z, w2.y, acc.y);
                acc.z = fmaf(hk.z, w2.z, acc.z); acc.w = fmaf(hk.z, w2.w, acc.w);
                acc.x = fmaf(hk.w, w3.x, acc.x); acc.y = fmaf(hk.w, w3.y, acc.y);
                acc.z = fmaf(hk.w, w3.z, acc.z); acc.w = fmaf(hk.w, w3.w, acc.w);
            }
            {   // tail k = 48, 49
                float2 ht = *h2t;
                const float4 w0 = w[48], w1 = w[49];
                acc.x = fmaf(ht.x, w0.x, acc.x); acc.y = fmaf(ht.x, w0.y, acc.y);
                acc.z = fmaf(ht.x, w0.z, acc.z); acc.w = fmaf(ht.x, w0.w, acc.w);
                acc.x = fmaf(ht.y, w1.x, acc.x); acc.y = fmaf(ht.y, w1.y, acc.y);
                acc.z = fmaf(ht.y, w1.z, acc.z); acc.w = fmaf(ht.y, w1.w, acc.w);
            }
            if (q == 0) acc.x += xv;
            else if (q == 1) acc.y += xv;
            else if (q == 2) acc.z += xv;
            else acc.w += xv;
            sPart[q][j] = acc;
        }
        __syncthreads();
        if (tid < 100) {
            float4 p0 = sPart[0][tid], p1 = sPart[1][tid];
            float4 p2 = sPart[2][tid], p3 = sPart[3][tid];
            float ai = p0.x + p1.x + p2.x + p3.x;
            float af = p0.y + p1.y + p2.y + p3.y;
            float ag = p0.z + p1.z + p2.z + p3.z;
            float ao = p0.w + p1.w + p2.w + p3.w;
            float ii = sigmoidf_(ai), ff = sigmoidf_(af);
            float gg = tanhf(ag), oo = sigmoidf_(ao);
            c = ff * c + ii * gg;
            float hv = oo * tanhf(c);
            sh[jbase + tid] = hv;
            unsigned long long pk = ((unsigned long long)(unsigned)(s + 1) << 32)
                                  | (unsigned long long)__float_as_uint(hv);
            __hip_atomic_store(&hxS[((size_t)((s & 1) * 256 + pid)) * 128 + tid], pk,
                               __ATOMIC_RELAXED, __HIP_MEMORY_SCOPE_AGENT);
            hv_prev = hv; t_prev = t;
        }
        __syncthreads();
    }
    // flush the final step's h row
    if (tid < 100 && t_prev >= 0)
        hout[((size_t)b * L_ + t_prev) * H_ + jbase + tid] = hv_prev;
    // frozen tail t in [len, 256): forward -> h_{len-1}, backward -> 0 (own units)
    for (int i = tid; i < (L_ - len) * 100; i += 512) {
        int t = len + i / 100, uu = jbase + i % 100;
        hout[((size_t)b * L_ + t) * H_ + uu] = dir ? 0.0f : sh[uu];
    }
}

// ---------------- scores + vproj ----------------
__global__ __launch_bounds__(256) void k_proj(const float* __restrict__ hf,
        const float* __restrict__ hb, const float* __restrict__ Weff,
        float* __restrict__ scores, float* __restrict__ vproj) {
    __shared__ float sW[ENC_ * 8];
    int tid = threadIdx.x;
    for (int i = tid; i < ENC_ * 8; i += 256) sW[i] = Weff[i];
    __syncthreads();
    int pos = blockIdx.x * 32 + (tid >> 3);
    int o = tid & 7;
    int b = pos >> 8, l = pos & 255;
    const float* hfr = hf + (size_t)pos * H_;
    const float* hbr = hb + (size_t)pos * H_;
    float s = 0.0f;
#pragma unroll 4
    for (int e = 0; e < H_; e++) s = fmaf(hfr[e], sW[e * 8 + o], s);
#pragma unroll 4
    for (int e = 0; e < H_; e++) s = fmaf(hbr[e], sW[(H_ + e) * 8 + o], s);
    if (o < NH_) scores[((size_t)b * NH_ + o) * L_ + l] = SCALING_ * s;
    else        vproj[(size_t)pos * NH_ + (o - NH_)] = s;
}

// ---------------- fused budget projection + finalize ----------------
// 64 blocks x 1024 threads. Group g = tid>>8 handles head g of batch b with
// group-local reductions (per-wave slots in red[16]); the 60-iter bisection
// is uniform across groups so block-wide barriers are legal. p stays in LDS
// (sp[4][256]) — never touches HBM. Math sequence identical to the old
// k_budget + k_final pair.
__global__ __launch_bounds__(1024) void k_bf(const float* __restrict__ scores,
        const int* __restrict__ lengths, const float* __restrict__ budget,
        const float* __restrict__ vproj, const float* __restrict__ out_b,
        float* __restrict__ dout) {
    __shared__ float sp[4][256];
    __shared__ float red[16];
    int b = blockIdx.x;
    int tid = threadIdx.x;
    int g = tid >> 8, l = tid & 255;
    int len = lengths[b];
    float bud = budget[b];
    bool m = (l < len);
    float s = m ? scores[((size_t)(b * NH_ + g)) * L_ + l] : -1.0e9f;

    // group-local sum/max helpers (inline; all 1024 threads call uniformly)
#define GSUM(OUTV, INV)                                                        \
    {                                                                          \
        float _v = (INV);                                                      \
        for (int off = 32; off > 0; off >>= 1) _v += __shfl_down(_v, off);     \
        __syncthreads();                                                       \
        if ((tid & 63) == 0) red[tid >> 6] = _v;                               \
        __syncthreads();                                                       \
        OUTV = red[g * 4] + red[g * 4 + 1] + red[g * 4 + 2] + red[g * 4 + 3];  \
        __syncthreads();                                                       \
    }
#define GMAX(OUTV, INV)                                                        \
    {                                                                          \
        float _v = (INV);                                                      \
        for (int off = 32; off > 0; off >>= 1) _v = fmaxf(_v, __shfl_down(_v, off)); \
        __syncthreads();                                                       \
        if ((tid & 63) == 0) red[tid >> 6] = _v;                               \
        __syncthreads();                                                       \
        OUTV = fmaxf(fmaxf(red[g * 4], red[g * 4 + 1]),                        \
                     fmaxf(red[g * 4 + 2], red[g * 4 + 3]));                   \
        __syncthreads();                                                       \
    }

    float p0 = fminf(fmaxf(s, 0.0f), 1.0f);
    float sum_p0; GSUM(sum_p0, p0);
    bool need = (sum_p0 > bud);
    float hi; GMAX(hi, m ? s : 0.0f);
    hi += 1.0f;
    float lo = 0.0f;
    for (int it = 0; it < 60; it++) {
        float mid = 0.5f * (lo + hi);
        float val; GSUM(val, fminf(fmaxf(s - mid, 0.0f), 1.0f));
        if (val > bud) lo = mid; else hi = mid;
    }
    float tau0 = 0.5f * (lo + hi);
    float r = s - tau0;
    bool fr  = (r > 0.0f) && (r < 1.0f) && m;
    bool h1f = (r >= 1.0f) && m;
    float n_free;   GSUM(n_free,   fr ? 1.0f : 0.0f);
    float sum_free; GSUM(sum_free, fr ? s : 0.0f);
    float n_hi;     GSUM(n_hi,     h1f ? 1.0f : 0.0f);
    float tau = (sum_free + n_hi - bud) / fmaxf(n_free, 1.0f);
    tau = (n_free > 0.0f) ? tau : tau0;
    float pv = fminf(fmaxf(s - tau, 0.0f), 1.0f);
    sp[g][l] = need ? pv : p0;
    __syncthreads();

    // finalize: threads of group 0 handle position l
    float contrib = 0.0f;
    if (g == 0) {
        float P0 = sp[0][l], P1 = sp[1][l], P2 = sp[2][l], P3 = sp[3][l];
        const float* vp = vproj + ((size_t)b * L_ + l) * NH_;
        contrib = P0 * vp[0] + P1 * vp[1] + P2 * vp[2] + P3 * vp[3];
        dout[B_ + (size_t)b * L_ + l] = m ? 0.25f * (P0 + P1 + P2 + P3) : 0.0f;
    }
    for (int off = 32; off > 0; off >>= 1) contrib += __shfl_down(contrib, off);
    __syncthreads();
    if ((tid & 63) == 0) red[tid >> 6] = contrib;
    __syncthreads();
    if (tid == 0) {
        float tot = 0.0f;
        for (int i = 0; i < 16; i++) tot += red[i];
        dout[b] = 1.0f / (1.0f + expf(-(tot + out_b[0])));
    }
#undef GSUM
#undef GMAX
}

// ---------------- launch ----------------
extern "C" void kernel_launch(void* const* d_in, const int* in_sizes, int n_in,
                              void* d_out, int out_size, void* d_ws, size_t ws_size,
                              hipStream_t stream) {
    const int*   x    = (const int*)d_in[0];
    const void*  mask = d_in[2];
    const float* embW = (const float*)d_in[3];
    const float* Wi_f = (const float*)d_in[4];
    const float* Wh_f = (const float*)d_in[5];
    const float* b_f  = (const float*)d_in[6];
    const float* Wi_b = (const float*)d_in[7];
    const float* Wh_b = (const float*)d_in[8];
    const float* b_b  = (const float*)d_in[9];
    const float* Wk   = (const float*)d_in[10];
    const float* Wv   = (const float*)d_in[11];
    const float* q    = (const float*)d_in[12];
    const float* Wo   = (const float*)d_in[13];
    const float* outW = (const float*)d_in[14];
    const float* outb = (const float*)d_in[15];
    float* dout = (float*)d_out;

    float* ws     = (float*)d_ws;
    float* xproj  = ws;                               // 26,214,400
    float* hf     = xproj + (size_t)16384 * 1600;     // 3,276,800
    float* hb     = hf + (size_t)16384 * 200;         // 3,276,800
    float* scores = hb + (size_t)16384 * 200;         // 65,536
    float* vproj  = scores + 65536;                   // 65,536
    float* p      = vproj + 65536;                    // 65,536 (unused now)
    float* Weff   = p + 65536;                        // 3,200
    float* w2     = Weff + 3200;                      // 400 (unused slot, kept)
    float* budget = w2 + 400;                         // 64
    int*   lengths= (int*)(budget + 64);              // 64
    float* Wp     = (float*)(lengths + 64);           // 320,000 packed Wh

    // hxS: 2 parity x 256 pid x 128 lanes x 8B = 512 KB agent-scope exchange.
    // Aliases scores+vproj (131,072 floats): dead until k_proj runs; harness
    // re-poisons (0xAA) each iteration; poison tag never matches 1..256.
    unsigned long long* hxS = (unsigned long long*)scores;

    // fused front: GEMM + prep + weff(w2 inline) + pack in ONE launch
    k_front<<<FR_PACK, 256, 0, stream>>>(x, embW, Wi_f, b_f, Wi_b, b_b, xproj,
                                         mask, lengths, budget,
                                         Wk, Wv, q, Wo, outW, Weff,
                                         Wh_f, Wh_b, Wp);

    {   // cooperative: all 256 blocks (1/CU) must be co-resident for pair sync
        const float4* Wp4 = (const float4*)Wp;
        void* args[] = { (void*)&xproj, (void*)&Wp4, (void*)&lengths,
                         (void*)&hf, (void*)&hb, (void*)&hxS };
        hipLaunchCooperativeKernel((const void*)k_lstm, dim3(256), dim3(512),
                                   args, 0, stream);
    }

    k_proj<<<(B_ * L_) / 32, 256, 0, stream>>>(hf, hb, Weff, scores, vproj);
    k_bf<<<B_, 1024, 0, stream>>>(scores, lengths, budget, vproj, outb, dout);
}

// Round 15
// 869.928 us; speedup vs baseline: 1.0007x; 1.0007x over previous
//
#include <hip/hip_runtime.h>
#include <math.h>

// Problem constants
#define B_      64
#define L_      256
#define V_      30000
#define E_      300
#define H_      200
#define G4_     800     // 4*H
#define ENC_    400
#define NH_     4
#define DH_     100
#define SCALING_ 1000.0f

__device__ __forceinline__ float sigmoidf_(float x) { return 1.0f / (1.0f + expf(-x)); }

// ---------------- block reductions (256 threads = 4 waves) ----------------
__device__ __forceinline__ float blockSum256(float v, float* red) {
    for (int off = 32; off > 0; off >>= 1) v += __shfl_down(v, off);
    __syncthreads();
    if ((threadIdx.x & 63) == 0) red[threadIdx.x >> 6] = v;
    __syncthreads();
    return red[0] + red[1] + red[2] + red[3];
}
__device__ __forceinline__ float blockMax256(float v, float* red) {
    for (int off = 32; off > 0; off >>= 1) v = fmaxf(v, __shfl_down(v, off));
    __syncthreads();
    if ((threadIdx.x & 63) == 0) red[threadIdx.x >> 6] = v;
    __syncthreads();
    return fmaxf(fmaxf(red[0], red[1]), fmaxf(red[2], red[3]));
}

// ---------------- fused front kernel ----------------
// Blocks [0,3200):        xproj GEMM tiles (128x64 tile, 8x4 micro — verbatim)
// Blocks [3200,3264):     prep (lengths+budget), 256 threads via blockSum256
// Blocks [3264,3277):     Weff, with w2 = Wo@outW recomputed cooperatively in
//                         LDS (same sequential j-loop -> bit-identical to the
//                         old k_w2), removing the w2->weff cross-kernel dep
// Blocks [3277,4527):     Wh gate-interleave pack (verbatim)
// All sub-tasks independent -> safe in one launch; everything completes
// before k_lstm at the kernel boundary. Saves 4 launches and lets the tiny
// tasks fill CUs concurrently with GEMM tiles. [measured r12: 863.7 us total]
// NOTE (r13): 8x8 micro @128x128 tile + budget/final fusion measured 870.6
// -> GEMM tiling is NOT the front binding factor; keep this verified config.
// NOTE (r14): container failed twice on THIS EXACT source (infra flake, same
// signature as r1); r12 measured it passing at 863.7 us.
#define GTM 128
#define GTN 64
#define GKC 16
#define SA_LD (GTM + 4)
#define SB_LD (GTN + 4)
#define FR_GEMM  3200
#define FR_PREP  (FR_GEMM + 64)     // 3264
#define FR_WEFF  (FR_PREP + 13)     // 3277
#define FR_PACK  (FR_WEFF + 1250)   // 4527 = grid size
__global__ __launch_bounds__(256) void k_front(const int* __restrict__ x,
        const float* __restrict__ embW,
        const float* __restrict__ Wi_f, const float* __restrict__ b_f,
        const float* __restrict__ Wi_b, const float* __restrict__ b_b,
        float* __restrict__ xproj,
        const void* __restrict__ maskraw, int* __restrict__ lengths,
        float* __restrict__ budget,
        const float* __restrict__ Wk, const float* __restrict__ Wv,
        const float* __restrict__ q, const float* __restrict__ Wo,
        const float* __restrict__ outW, float* __restrict__ Weff,
        const float* __restrict__ Wh_f, const float* __restrict__ Wh_b,
        float* __restrict__ Wp) {
    __shared__ float sA[GKC * SA_LD];
    __shared__ float sB[GKC * SB_LD];
    __shared__ int srow[GTM];
    __shared__ float sOW[ENC_];
    __shared__ float sW2[ENC_];
    __shared__ float red[4];
    int tid = threadIdx.x;
    int blk = blockIdx.x;

    if (blk < FR_GEMM) {
        // ---------------- xproj GEMM tile (verbatim round-4 code) ----------
        int tm0 = (blk & 127) * GTM;
        int tn0 = (blk >> 7) * GTN;
        if (tid < GTM) srow[tid] = x[tm0 + tid];
        __syncthreads();
        int tx = tid & 15, ty = tid >> 4;
        float acc[8][4];
#pragma unroll
        for (int u = 0; u < 8; u++)
#pragma unroll
            for (int v = 0; v < 4; v++) acc[u][v] = 0.0f;

        int mm = tid >> 1, kk8 = (tid & 1) * 8;
        int kkB = tid >> 4, c4 = (tid & 15) * 4;
        int colB = tn0 + c4;
        const float* bbase = (colB < G4_) ? (Wi_f + colB) : (Wi_b + (colB - G4_));

        for (int k0 = 0; k0 < E_; k0 += GKC) {
            const float* arow = embW + (size_t)srow[mm] * E_ + k0 + kk8;
            if (k0 + GKC <= E_) {
                float4 a0 = *(const float4*)(arow);
                float4 a1 = *(const float4*)(arow + 4);
                sA[(kk8 + 0) * SA_LD + mm] = a0.x;
                sA[(kk8 + 1) * SA_LD + mm] = a0.y;
                sA[(kk8 + 2) * SA_LD + mm] = a0.z;
                sA[(kk8 + 3) * SA_LD + mm] = a0.w;
                sA[(kk8 + 4) * SA_LD + mm] = a1.x;
                sA[(kk8 + 5) * SA_LD + mm] = a1.y;
                sA[(kk8 + 6) * SA_LD + mm] = a1.z;
                sA[(kk8 + 7) * SA_LD + mm] = a1.w;
            } else {
#pragma unroll
                for (int i = 0; i < 8; i++) {
                    int k = k0 + kk8 + i;
                    sA[(kk8 + i) * SA_LD + mm] = (k < E_) ? arow[i] : 0.0f;
                }
            }
            {
                int kB = k0 + kkB;
                float4 bv = make_float4(0.f, 0.f, 0.f, 0.f);
                if (kB < E_) bv = *(const float4*)(bbase + (size_t)kB * G4_);
                *(float4*)&sB[kkB * SB_LD + c4] = bv;
            }
            __syncthreads();
#pragma unroll
            for (int kk2 = 0; kk2 < GKC; kk2++) {
                float4 a0 = *(const float4*)&sA[kk2 * SA_LD + ty * 8];
                float4 a1 = *(const float4*)&sA[kk2 * SA_LD + ty * 8 + 4];
                float4 b0 = *(const float4*)&sB[kk2 * SB_LD + tx * 4];
                float av[8] = {a0.x, a0.y, a0.z, a0.w, a1.x, a1.y, a1.z, a1.w};
                float bv[4] = {b0.x, b0.y, b0.z, b0.w};
#pragma unroll
                for (int u = 0; u < 8; u++)
#pragma unroll
                    for (int v = 0; v < 4; v++) acc[u][v] = fmaf(av[u], bv[v], acc[u][v]);
            }
            __syncthreads();
        }
        int col = tn0 + tx * 4;
        float4 bias = (col < G4_) ? *(const float4*)(b_f + col)
                                  : *(const float4*)(b_b + (col - G4_));
#pragma unroll
        for (int u = 0; u < 8; u++) {
            int m = tm0 + ty * 8 + u;
            float4 o;
            o.x = acc[u][0] + bias.x;
            o.y = acc[u][1] + bias.y;
            o.z = acc[u][2] + bias.z;
            o.w = acc[u][3] + bias.w;
            *(float4*)&xproj[(size_t)m * 1600 + col] = o;
        }
    } else if (blk < FR_PREP) {
        // ---------------- prep: lengths + budget (256 thr, 1 elem each) ----
        int b = blk - FR_GEMM;
        const unsigned char* mb = (const unsigned char*)maskraw;
        bool is_byte = (mb[1] != 0);
        const int* mi = (const int*)maskraw;
        int v = is_byte ? (int)mb[b * L_ + tid] : mi[b * L_ + tid];
        float cnt = blockSum256((v != 0) ? 1.0f : 0.0f, red);
        if (tid == 0) {
            int c = (int)(cnt + 0.5f);
            lengths[b] = c;
            budget[b] = rintf(0.2f * (float)c);
        }
    } else if (blk < FR_WEFF) {
        // ---------------- Weff (w2 recomputed cooperatively, bit-identical) -
        for (int i = tid; i < ENC_; i += 256) sOW[i] = outW[i];
        __syncthreads();
        for (int e2 = tid; e2 < ENC_; e2 += 256) {
            float s = 0.0f;
            for (int j2 = 0; j2 < ENC_; j2++)
                s = fmaf(Wo[(size_t)e2 * ENC_ + j2], sOW[j2], s);
            sW2[e2] = s;
        }
        __syncthreads();
        int idx = (blk - FR_PREP) * 256 + tid;
        if (idx < ENC_ * 8) {
            int e = idx >> 3, c = idx & 7;
            int h = c & 3;
            bool isV = (c >= 4);
            const float* M = isV ? Wv : Wk;
            float s = 0.0f;
            for (int d = 0; d < DH_; d++) {
                float wq = isV ? sW2[h * DH_ + d] : q[h * DH_ + d];
                s = fmaf(M[(size_t)e * ENC_ + h * DH_ + d], wq, s);
            }
            Weff[idx] = s;
        }
    } else {
        // ---------------- pack Wh gate-interleaved (verbatim) --------------
        int idx = (blk - FR_WEFF) * 256 + tid;   // covers 2*200*200*4 = 320000
        if (idx < 2 * H_ * H_ * 4) {
            int dir = idx / (H_ * H_ * 4);
            int r = idx % (H_ * H_ * 4);
            int k = r / (H_ * 4);
            int r2 = r % (H_ * 4);
            int j = r2 >> 2, g = r2 & 3;
            const float* Wh = dir ? Wh_b : Wh_f;
            Wp[idx] = Wh[(size_t)k * G4_ + g * H_ + j];
        }
    }
}

// ---------------- biLSTM v7: pair-split + exchange hidden under own-half matvec ----
// 256 blocks x 512 threads, cooperative (1 block/CU). 64-bit {tag,h} relaxed
// agent atomics, parity slots. Wave-role split: poll at top of step hidden
// under own-half matvec; monotonic LDS release counter.
// Verified-best k_lstm (499-502 us across r4/r11/r12/r13). Attack attempts
// all regressed on HW: dual-publish L2 fast path (+125), store/load
// micro-reorder (+22), lgkm-only barriers + 4-deep poll (+49),
// dual-chain-per-pair (+461: per-chain-step cost unchanged -> cost is the
// poll's L3 fetch + serial structure, not detection lag). Single-CU is
// impossible: 640 KB weights > 512 KB/CU register file.
#define KS2 50
__global__ __launch_bounds__(512, 2) void k_lstm(const float* __restrict__ xproj,
        const float4* __restrict__ Wp, const int* __restrict__ lengths,
        float* __restrict__ hf, float* __restrict__ hb,
        unsigned long long* __restrict__ hxS) {
    int pid = blockIdx.x;                 // 0..255
    int chain = pid & 127;
    int half = pid >> 7;
    int partner = pid ^ 128;              // same XCD under %8 round-robin
    int b = chain >> 1, dir = chain & 1;
    int jbase = half * 100;
    const float4* W = Wp + (size_t)dir * H_ * H_;
    float* hout = dir ? hb : hf;
    int len = lengths[b];
    __shared__ float sh[256];             // full h(t), 200 used
    __shared__ float4 sPart[4][128];      // [q][j] partial gate quads
    __shared__ int scnt;                  // monotonic poll-release counter
    int tid = threadIdx.x;
    int q = tid >> 7, j = tid & 127;
    bool act = (j < 100);
    int u = jbase + j;
    bool partnerQ = ((q >> 1) == (half ^ 1));   // this q-slice reads partner half
    int pq0 = (half ^ 1) * 2;                    // first partner-q group

    // preload this thread's weight half-slice into registers (stays resident)
    float4 w[KS2];
    if (act) {
        const float4* wp = W + (size_t)(q * KS2) * H_ + u;
#pragma unroll
        for (int k = 0; k < KS2; k++) w[k] = wp[(size_t)k * H_];
    }
    if (tid < H_) sh[tid] = 0.0f;
    if (tid == 0) scnt = 0;
    float c = 0.0f;
    float hv_prev = 0.0f;
    int t_prev = -1;
    __syncthreads();
    const float* xp = xproj + (size_t)b * L_ * 1600 + dir * G4_;
    const float4* h4 = (const float4*)(sh + q * KS2);
    const float2* h2t = (const float2*)(sh + q * KS2 + 48);

    for (int s = 0; s < len; s++) {
        int t = dir ? (len - 1 - s) : s;
        // previous step's HBM store, drained under this step's matvec
        if (tid < 100 && t_prev >= 0)
            hout[((size_t)b * L_ + t_prev) * H_ + jbase + tid] = hv_prev;
        // pollers: stage partner h(s-1) into sh, then release via LDS counter
        if (s > 0 && q == pq0 && j < 100) {
            size_t idx = ((size_t)(((s - 1) & 1) * 256 + partner)) * 128 + j;
            unsigned long long got;
            do {
                got = __hip_atomic_load(&hxS[idx], __ATOMIC_RELAXED,
                                        __HIP_MEMORY_SCOPE_AGENT);
            } while ((unsigned)(got >> 32) != (unsigned)s);
            sh[(half ^ 1) * 100 + j] = __uint_as_float((unsigned)got);
            __threadfence_block();
            __hip_atomic_fetch_add(&scnt, 1, __ATOMIC_RELAXED,
                                   __HIP_MEMORY_SCOPE_WORKGROUP);
        }
        if (act) {
            if (partnerQ && s > 0) {
                int target = 100 * s;
                while (__hip_atomic_load(&scnt, __ATOMIC_RELAXED,
                                         __HIP_MEMORY_SCOPE_WORKGROUP) < target) {}
            }
            float xv = xp[(size_t)t * 1600 + q * H_ + u];
            float4 acc = make_float4(0.f, 0.f, 0.f, 0.f);
#pragma unroll
            for (int k4 = 0; k4 < 12; k4++) {
                float4 hk = h4[k4];
                const float4 w0 = w[k4 * 4 + 0], w1 = w[k4 * 4 + 1];
                const float4 w2 = w[k4 * 4 + 2], w3 = w[k4 * 4 + 3];
                acc.x = fmaf(hk.x, w0.x, acc.x); acc.y = fmaf(hk.x, w0.y, acc.y);
                acc.z = fmaf(hk.x, w0.z, acc.z); acc.w = fmaf(hk.x, w0.w, acc.w);
                acc.x = fmaf(hk.y, w1.x, acc.x); acc.y = fmaf(hk.y, w1.y, acc.y);
                acc.z = fmaf(hk.y, w1.z, acc.z); acc.w = fmaf(hk.y, w1.w, acc.w);
                acc.x = fmaf(hk.z, w2.x, acc.x); acc.y = fmaf(hk.z, w2.y, acc.y);
                acc.z = fmaf(hk.z, w2.z, acc.z); acc.w = fmaf(hk.z, w2.w, acc.w);
                acc.x = fmaf(hk.w, w3.x, acc.x); acc.y = fmaf(hk.w, w3.y, acc.y);
                acc.z = fmaf(hk.w, w3.z, acc.z); acc.w = fmaf(hk.w, w3.w, acc.w);
            }
            {   // tail k = 48, 49
                float2 ht = *h2t;
                const float4 w0 = w[48], w1 = w[49];
                acc.x = fmaf(ht.x, w0.x, acc.x); acc.y = fmaf(ht.x, w0.y, acc.y);
                acc.z = fmaf(ht.x, w0.z, acc.z); acc.w = fmaf(ht.x, w0.w, acc.w);
                acc.x = fmaf(ht.y, w1.x, acc.x); acc.y = fmaf(ht.y, w1.y, acc.y);
                acc.z = fmaf(ht.y, w1.z, acc.z); acc.w = fmaf(ht.y, w1.w, acc.w);
            }
            if (q == 0) acc.x += xv;
            else if (q == 1) acc.y += xv;
            else if (q == 2) acc.z += xv;
            else acc.w += xv;
            sPart[q][j] = acc;
        }
        __syncthreads();
        if (tid < 100) {
            float4 p0 = sPart[0][tid], p1 = sPart[1][tid];
            float4 p2 = sPart[2][tid], p3 = sPart[3][tid];
            float ai = p0.x + p1.x + p2.x + p3.x;
            float af = p0.y + p1.y + p2.y + p3.y;
            float ag = p0.z + p1.z + p2.z + p3.z;
            float ao = p0.w + p1.w + p2.w + p3.w;
            float ii = sigmoidf_(ai), ff = sigmoidf_(af);
            float gg = tanhf(ag), oo = sigmoidf_(ao);
            c = ff * c + ii * gg;
            float hv = oo * tanhf(c);
            sh[jbase + tid] = hv;
            unsigned long long pk = ((unsigned long long)(unsigned)(s + 1) << 32)
                                  | (unsigned long long)__float_as_uint(hv);
            __hip_atomic_store(&hxS[((size_t)((s & 1) * 256 + pid)) * 128 + tid], pk,
                               __ATOMIC_RELAXED, __HIP_MEMORY_SCOPE_AGENT);
            hv_prev = hv; t_prev = t;
        }
        __syncthreads();
    }
    // flush the final step's h row
    if (tid < 100 && t_prev >= 0)
        hout[((size_t)b * L_ + t_prev) * H_ + jbase + tid] = hv_prev;
    // frozen tail t in [len, 256): forward -> h_{len-1}, backward -> 0 (own units)
    for (int i = tid; i < (L_ - len) * 100; i += 512) {
        int t = len + i / 100, uu = jbase + i % 100;
        hout[((size_t)b * L_ + t) * H_ + uu] = dir ? 0.0f : sh[uu];
    }
}

// ---------------- scores + vproj ----------------
__global__ __launch_bounds__(256) void k_proj(const float* __restrict__ hf,
        const float* __restrict__ hb, const float* __restrict__ Weff,
        float* __restrict__ scores, float* __restrict__ vproj) {
    __shared__ float sW[ENC_ * 8];
    int tid = threadIdx.x;
    for (int i = tid; i < ENC_ * 8; i += 256) sW[i] = Weff[i];
    __syncthreads();
    int pos = blockIdx.x * 32 + (tid >> 3);
    int o = tid & 7;
    int b = pos >> 8, l = pos & 255;
    const float* hfr = hf + (size_t)pos * H_;
    const float* hbr = hb + (size_t)pos * H_;
    float s = 0.0f;
#pragma unroll 4
    for (int e = 0; e < H_; e++) s = fmaf(hfr[e], sW[e * 8 + o], s);
#pragma unroll 4
    for (int e = 0; e < H_; e++) s = fmaf(hbr[e], sW[(H_ + e) * 8 + o], s);
    if (o < NH_) scores[((size_t)b * NH_ + o) * L_ + l] = SCALING_ * s;
    else        vproj[(size_t)pos * NH_ + (o - NH_)] = s;
}

// ---------------- budget projection ----------------
__global__ __launch_bounds__(256) void k_budget(const float* __restrict__ scores,
        const int* __restrict__ lengths, const float* __restrict__ budget,
        float* __restrict__ p) {
    __shared__ float red[4];
    int bh = blockIdx.x;
    int b = bh >> 2;
    int l = threadIdx.x;
    int len = lengths[b];
    float bud = budget[b];
    bool m = (l < len);
    float s = m ? scores[(size_t)bh * L_ + l] : -1.0e9f;
    float p0 = fminf(fmaxf(s, 0.0f), 1.0f);
    float sum_p0 = blockSum256(p0, red);
    bool need = (sum_p0 > bud);
    float hi = blockMax256(m ? s : 0.0f, red) + 1.0f;
    float lo = 0.0f;
    for (int it = 0; it < 60; it++) {
        float mid = 0.5f * (lo + hi);
        float val = blockSum256(fminf(fmaxf(s - mid, 0.0f), 1.0f), red);
        if (val > bud) lo = mid; else hi = mid;
    }
    float tau0 = 0.5f * (lo + hi);
    float r = s - tau0;
    bool fr  = (r > 0.0f) && (r < 1.0f) && m;
    bool h1f = (r >= 1.0f) && m;
    float n_free   = blockSum256(fr ? 1.0f : 0.0f, red);
    float sum_free = blockSum256(fr ? s : 0.0f, red);
    float n_hi     = blockSum256(h1f ? 1.0f : 0.0f, red);
    float tau = (sum_free + n_hi - bud) / fmaxf(n_free, 1.0f);
    tau = (n_free > 0.0f) ? tau : tau0;
    float pv = fminf(fmaxf(s - tau, 0.0f), 1.0f);
    p[(size_t)bh * L_ + l] = need ? pv : p0;
}

// ---------------- finalize ----------------
__global__ __launch_bounds__(256) void k_final(const float* __restrict__ p,
        const float* __restrict__ vproj, const int* __restrict__ lengths,
        const float* __restrict__ out_b, float* __restrict__ dout) {
    __shared__ float red[4];
    int b = blockIdx.x;
    int l = threadIdx.x;
    int len = lengths[b];
    float p0 = p[((size_t)b * NH_ + 0) * L_ + l];
    float p1 = p[((size_t)b * NH_ + 1) * L_ + l];
    float p2 = p[((size_t)b * NH_ + 2) * L_ + l];
    float p3 = p[((size_t)b * NH_ + 3) * L_ + l];
    dout[B_ + (size_t)b * L_ + l] = (l < len) ? 0.25f * (p0 + p1 + p2 + p3) : 0.0f;
    const float* vp = vproj + ((size_t)b * L_ + l) * NH_;
    float contrib = p0 * vp[0] + p1 * vp[1] + p2 * vp[2] + p3 * vp[3];
    float tot = blockSum256(contrib, red);
    if (l == 0) dout[b] = 1.0f / (1.0f + expf(-(tot + out_b[0])));
}

// ---------------- launch ----------------
extern "C" void kernel_launch(void* const* d_in, const int* in_sizes, int n_in,
                              void* d_out, int out_size, void* d_ws, size_t ws_size,
                              hipStream_t stream) {
    const int*   x    = (const int*)d_in[0];
    const void*  mask = d_in[2];
    const float* embW = (const float*)d_in[3];
    const float* Wi_f = (const float*)d_in[4];
    const float* Wh_f = (const float*)d_in[5];
    const float* b_f  = (const float*)d_in[6];
    const float* Wi_b = (const float*)d_in[7];
    const float* Wh_b = (const float*)d_in[8];
    const float* b_b  = (const float*)d_in[9];
    const float* Wk   = (const float*)d_in[10];
    const float* Wv   = (const float*)d_in[11];
    const float* q    = (const float*)d_in[12];
    const float* Wo   = (const float*)d_in[13];
    const float* outW = (const float*)d_in[14];
    const float* outb = (const float*)d_in[15];
    float* dout = (float*)d_out;

    float* ws     = (float*)d_ws;
    float* xproj  = ws;                               // 26,214,400
    float* hf     = xproj + (size_t)16384 * 1600;     // 3,276,800
    float* hb     = hf + (size_t)16384 * 200;         // 3,276,800
    float* scores = hb + (size_t)16384 * 200;         // 65,536
    float* vproj  = scores + 65536;                   // 65,536
    float* p      = vproj + 65536;                    // 65,536
    float* Weff   = p + 65536;                        // 3,200
    float* w2     = Weff + 3200;                      // 400 (unused slot, kept)
    float* budget = w2 + 400;                         // 64
    int*   lengths= (int*)(budget + 64);              // 64
    float* Wp     = (float*)(lengths + 64);           // 320,000 packed Wh

    // hxS: 2 parity x 256 pid x 128 lanes x 8B = 512 KB agent-scope exchange.
    // Aliases scores+vproj (131,072 floats): dead until k_proj runs; harness
    // re-poisons (0xAA) each iteration; poison tag never matches 1..256.
    unsigned long long* hxS = (unsigned long long*)scores;

    // fused front: GEMM + prep + weff(w2 inline) + pack in ONE launch
    k_front<<<FR_PACK, 256, 0, stream>>>(x, embW, Wi_f, b_f, Wi_b, b_b, xproj,
                                         mask, lengths, budget,
                                         Wk, Wv, q, Wo, outW, Weff,
                                         Wh_f, Wh_b, Wp);

    {   // cooperative: all 256 blocks (1/CU) must be co-resident for pair sync
        const float4* Wp4 = (const float4*)Wp;
        void* args[] = { (void*)&xproj, (void*)&Wp4, (void*)&lengths,
                         (void*)&hf, (void*)&hb, (void*)&hxS };
        hipLaunchCooperativeKernel((const void*)k_lstm, dim3(256), dim3(512),
                                   args, 0, stream);
    }

    k_proj<<<(B_ * L_) / 32, 256, 0, stream>>>(hf, hb, Weff, scores, vproj);
    k_budget<<<B_ * NH_, 256, 0, stream>>>(scores, lengths, budget, p);
    k_final<<<B_, 256, 0, stream>>>(p, vproj, lengths, outb, dout);
}